// Round 1
// baseline (246.565 us; speedup 1.0000x reference)
//
#include <hip/hip_runtime.h>

// Problem constants (from reference): BS=16, H=W=192, C=64, K=3, R=13, TAU=0.5, EPS=1e-8
// Vectors: p[b, i, d] with i in [0,26) (i<13 from f1, else f2), d = pixel_k*64 + c, D=576.
// loss = mean over (b,i) of [ logsumexp_{j != i} sim[b,i,j] - sim[b,i,(i+13)%26] ]
// sim = (p_i . p_j) / (max(|p_i|,eps) * max(|p_j|,eps)) * (1/TAU)

#define SM_STRIDE 68   // 64 floats + 4 pad to break 256B bank stride, keeps 16B alignment

// Kernel 1: one block per (batch b, pixel k). Gather 26 x 64-ch pixel slices to LDS,
// compute partial 26x26 Gram over those 64 channels, write slab to ws[(b*9+k)*676 + e].
__global__ __launch_bounds__(256) void gram_partial_kernel(
    const float* __restrict__ f1, const float* __restrict__ f2,
    const int* __restrict__ h_idx, const int* __restrict__ w_idx,
    float* __restrict__ gpart)
{
    __shared__ float sm[26 * SM_STRIDE];
    const int bid = blockIdx.x;
    const int b = bid / 9;
    const int k = bid - b * 9;
    const int tid = threadIdx.x;

    // Gather: 26 vectors x 16 float4 (64 channels) = 416 float4 loads.
    for (int q = tid; q < 26 * 16; q += 256) {
        const int i  = q >> 4;     // vector 0..25
        const int c4 = q & 15;     // float4 index within channel dim
        const int r  = (i < 13) ? i : (i - 13);
        const int flat = (r * 16 + b) * 9 + k;   // region-major, batch, pixel ordering
        const int h = h_idx[flat];
        const int w = w_idx[flat];
        const float* f = (i < 13) ? f1 : f2;
        const float4 v = *reinterpret_cast<const float4*>(
            f + (((size_t)b * 192 + h) * 192 + w) * 64 + c4 * 4);
        *reinterpret_cast<float4*>(&sm[i * SM_STRIDE + c4 * 4]) = v;
    }
    __syncthreads();

    // Partial Gram: 13x13 grid of 2x2 tiles, one tile per thread (169 active threads).
    if (tid < 169) {
        const int ti = tid / 13, tj = tid - ti * 13;
        const int i0 = ti * 2, j0 = tj * 2;
        const float4* pa0 = reinterpret_cast<const float4*>(&sm[i0 * SM_STRIDE]);
        const float4* pa1 = reinterpret_cast<const float4*>(&sm[(i0 + 1) * SM_STRIDE]);
        const float4* pb0 = reinterpret_cast<const float4*>(&sm[j0 * SM_STRIDE]);
        const float4* pb1 = reinterpret_cast<const float4*>(&sm[(j0 + 1) * SM_STRIDE]);
        float a00 = 0.f, a01 = 0.f, a10 = 0.f, a11 = 0.f;
        #pragma unroll
        for (int c4 = 0; c4 < 16; ++c4) {
            const float4 x0 = pa0[c4], x1 = pa1[c4], y0 = pb0[c4], y1 = pb1[c4];
            a00 += x0.x * y0.x + x0.y * y0.y + x0.z * y0.z + x0.w * y0.w;
            a01 += x0.x * y1.x + x0.y * y1.y + x0.z * y1.z + x0.w * y1.w;
            a10 += x1.x * y0.x + x1.y * y0.y + x1.z * y0.z + x1.w * y0.w;
            a11 += x1.x * y1.x + x1.y * y1.y + x1.z * y1.z + x1.w * y1.w;
        }
        float* dst = gpart + ((size_t)b * 9 + k) * 676;
        dst[(i0    ) * 26 + j0    ] = a00;
        dst[(i0    ) * 26 + j0 + 1] = a01;
        dst[(i0 + 1) * 26 + j0    ] = a10;
        dst[(i0 + 1) * 26 + j0 + 1] = a11;
    }
}

// Kernel 2: one block per batch. Reduce 9 partial Grams, normalize, per-row
// logsumexp over j != i, accumulate scaled loss into out[0].
__global__ __launch_bounds__(256) void loss_kernel(
    const float* __restrict__ gpart, float* __restrict__ out)
{
    __shared__ float g[676];
    __shared__ float inv[26];
    __shared__ float rowloss[26];
    const int b = blockIdx.x;
    const int tid = threadIdx.x;
    const float* src = gpart + (size_t)b * 9 * 676;

    for (int e = tid; e < 676; e += 256) {
        float s = 0.f;
        #pragma unroll
        for (int k = 0; k < 9; ++k) s += src[k * 676 + e];
        g[e] = s;
    }
    __syncthreads();

    if (tid < 26) {
        const float d = g[tid * 26 + tid];          // |p_i|^2
        float n = sqrtf(d);
        n = fmaxf(n, 1e-8f);                        // max(norm, EPS)
        inv[tid] = 1.0f / n;
    }
    __syncthreads();

    if (tid < 26) {
        const int i = tid;
        const float invi = inv[i];
        const int posj = (i + 13) % 26;
        float s[26];
        float m = -1e30f;
        #pragma unroll
        for (int j = 0; j < 26; ++j) {
            const float v = g[i * 26 + j] * invi * inv[j] * 2.0f;  // 1/TAU = 2
            s[j] = v;
            if (j != i) m = fmaxf(m, v);
        }
        float sum = 0.f;
        #pragma unroll
        for (int j = 0; j < 26; ++j) {
            if (j != i) sum += expf(s[j] - m);
        }
        rowloss[i] = (logf(sum) + m) - s[posj];
    }
    __syncthreads();

    if (tid == 0) {
        float t = 0.f;
        #pragma unroll
        for (int i = 0; i < 26; ++i) t += rowloss[i];
        atomicAdd(out, t * (1.0f / 416.0f));        // mean over 16*26 rows
    }
}

extern "C" void kernel_launch(void* const* d_in, const int* in_sizes, int n_in,
                              void* d_out, int out_size, void* d_ws, size_t ws_size,
                              hipStream_t stream) {
    const float* f1   = (const float*)d_in[0];
    const float* f2   = (const float*)d_in[1];
    // d_in[2] = b_idx (redundant: equals broadcast batch index)
    const int* h_idx  = (const int*)d_in[3];
    const int* w_idx  = (const int*)d_in[4];
    float* out   = (float*)d_out;
    float* gpart = (float*)d_ws;   // needs 16*9*676*4 = 389,376 bytes

    hipMemsetAsync(out, 0, sizeof(float), stream);
    hipLaunchKernelGGL(gram_partial_kernel, dim3(16 * 9), dim3(256), 0, stream,
                       f1, f2, h_idx, w_idx, gpart);
    hipLaunchKernelGGL(loss_kernel, dim3(16), dim3(256), 0, stream, gpart, out);
}